// Round 5
// baseline (2192.457 us; speedup 1.0000x reference)
//
#include <hip/hip_runtime.h>
#include <stdint.h>

typedef unsigned short u16;
typedef unsigned int u32;

#define B_ 32
#define L_ 512
#define T_ 4096
#define E_ 256
#define F_ 256

// fp32 duration predictor params
#define TW 16
#define NH (TW + 2)
#define NX (TW + 4)
#define RS 20

// MFMA predictor params
#define MTW 62
#define MROWS 64
#define XROWS 66
#define XSTR 264          // u16 per LDS row (528B) -> conflict-clean b128 reads
#define NBLK 67           // ceil(4096/62)
#define KW 768
#define WMAT (KW * F_)

#define NMFMA (B_ * NBLK) // 2144

typedef short bf16x8 __attribute__((ext_vector_type(8)));
typedef float f32x4 __attribute__((ext_vector_type(4)));
union Frag { uint4 u; bf16x8 b; };

struct MfmaSmem {
    u16 xs[XROWS * XSTR];
    float2 red[MROWS][4];
    float m_l[MROWS], inv_l[MROWS];
};
struct DurSmem {
    float buf[E_ * RS];
    float red_s[NH][4], red_q[NH][4];
    float m_l[NH], inv_l[NH];
};
union SmemU { MfmaSmem m; DurSmem d; };

__device__ __forceinline__ float b2f(u16 u) {
    union { u32 i; float f; } x; x.i = ((u32)u) << 16; return x.f;
}
__device__ __forceinline__ u16 f2b(float f) {
    union { u32 i; float f; } x; x.f = f;
    u32 r = x.i + 0x7FFFu + ((x.i >> 16) & 1u);
    return (u16)(r >> 16);
}
__device__ __forceinline__ float blo(u32 v) { return b2f((u16)(v & 0xffffu)); }
__device__ __forceinline__ float bhi(u32 v) { return b2f((u16)(v >> 16)); }

// ---------- weight prep: fp32 [kk][f] -> bf16 transposed [f][kk] ----------
__global__ void prep_w_kernel(const float* __restrict__ W1all,
                              const float* __restrict__ W2all,
                              u16* __restrict__ dst) {
    const int g = blockIdx.x * 256 + threadIdx.x;
    const int mat = g / WMAT, rem = g % WMAT;
    const int kk = rem >> 8, f = rem & 255;
    const float* src = ((mat & 1) ? W2all : W1all) + ((mat >> 1) + 1) * (3 * E_ * F_);
    dst[mat * WMAT + f * KW + kk] = f2b(src[kk * 256 + f]);
}

// ---------- bucketize both targets (bins cached in LDS) ----------
__global__ void bucket_kernel(const float* __restrict__ pt, const float* __restrict__ et,
                              const float* __restrict__ pbins, const float* __restrict__ ebins,
                              int* __restrict__ pb, int* __restrict__ eb) {
    __shared__ float pbs[256], ebs[256];
    const int tid = threadIdx.x;
    pbs[tid] = pbins[tid]; ebs[tid] = ebins[tid];
    __syncthreads();
    const int i = blockIdx.x * 256 + tid;
    {
        const float v = pt[i];
        int lo = 0, hi = 256;
        while (lo < hi) { int mid = (lo + hi) >> 1; if (pbs[mid] < v) lo = mid + 1; else hi = mid; }
        pb[i] = lo > 255 ? 255 : lo;
    }
    {
        const float v = et[i];
        int lo = 0, hi = 256;
        while (lo < hi) { int mid = (lo + hi) >> 1; if (ebs[mid] < v) lo = mid + 1; else hi = mid; }
        eb[i] = lo > 255 ? 255 : lo;
    }
}

// ---------- length-regulate (BF16: write bf16 to ws; else fp32 to out region) ----------
template <bool BF16>
__global__ __launch_bounds__(512) void lr_gather_kernel(
    const float* __restrict__ hidden, const int* __restrict__ dur,
    u16* __restrict__ xw, float* __restrict__ xf) {
    __shared__ int cs[L_];
    const int tid = threadIdx.x;
    const int b = blockIdx.x >> 5;
    const int f0 = (blockIdx.x & 31) * 128;
    cs[tid] = dur[b * L_ + tid];
    __syncthreads();
    for (int off = 1; off < L_; off <<= 1) {
        int t = (tid >= off) ? cs[tid - off] : 0;
        __syncthreads();
        cs[tid] += t;
        __syncthreads();
    }
    const int total = cs[L_ - 1];
    const int g = tid & 63;
    const int fr = tid >> 6;
#pragma unroll
    for (int pass = 0; pass < 16; ++pass) {
        const int t = f0 + pass * 8 + fr;
        int lo = 0, hi = L_;
        while (lo < hi) { int mid = (lo + hi) >> 1; if (cs[mid] <= t) lo = mid + 1; else hi = mid; }
        float4 v = make_float4(0.f, 0.f, 0.f, 0.f);
        if (t < total) {
            const int id = lo < (L_ - 1) ? lo : (L_ - 1);
            v = *(const float4*)(hidden + ((size_t)(b * L_ + id)) * E_ + g * 4);
        }
        if (BF16) {
            uint2 pk = make_uint2((u32)f2b(v.x) | ((u32)f2b(v.y) << 16),
                                  (u32)f2b(v.z) | ((u32)f2b(v.w) << 16));
            *(uint2*)(xw + ((size_t)(b * T_ + t)) * E_ + g * 4) = pk;
        } else {
            *(float4*)(xf + ((size_t)(b * T_ + t)) * E_ + g * 4) = v;
        }
    }
}

// ---------- x2 = x + pemb[pbkt]  (in-place on bf16 x in ws) ----------
__global__ void x2_kernel(u16* __restrict__ xw, const int* __restrict__ pbkt,
                          const float* __restrict__ pemb) {
#pragma unroll
    for (int it = 0; it < 8; ++it) {
        const int k = blockIdx.x * 2048 + it * 256 + threadIdx.x;   // uint4 id
        const int bt = k >> 5, c8 = k & 31;
        const int kb = pbkt[bt];
        u16* xp = xw + (size_t)bt * E_ + c8 * 8;
        uint4 xv = *(const uint4*)xp;
        const float4 e0 = *(const float4*)(pemb + (size_t)kb * E_ + c8 * 8);
        const float4 e1 = *(const float4*)(pemb + (size_t)kb * E_ + c8 * 8 + 4);
        uint4 o;
        o.x = (u32)f2b(blo(xv.x) + e0.x) | ((u32)f2b(bhi(xv.x) + e0.y) << 16);
        o.y = (u32)f2b(blo(xv.y) + e0.z) | ((u32)f2b(bhi(xv.y) + e0.w) << 16);
        o.z = (u32)f2b(blo(xv.z) + e1.x) | ((u32)f2b(bhi(xv.z) + e1.y) << 16);
        o.w = (u32)f2b(blo(xv.w) + e1.z) | ((u32)f2b(bhi(xv.w) + e1.w) << 16);
        *(uint4*)xp = o;
    }
}

// ---------- fallback: fused bucketize + out = x + emb (fp32, in-place) ----------
__global__ void addemb_kernel(const float* __restrict__ x, const float* __restrict__ tgt,
                              const float* __restrict__ bins, const float* __restrict__ emb,
                              float* __restrict__ outp) {
    const int i = blockIdx.x * blockDim.x + threadIdx.x;
    const int g = i & 63, bt = i >> 6;
    const float v = tgt[bt];
    int lo = 0, hi = 256;
    while (lo < hi) { int mid = (lo + hi) >> 1; if (bins[mid] < v) lo = mid + 1; else hi = mid; }
    const int k = lo > 255 ? 255 : lo;
    float4 xv = *(const float4*)(x + (size_t)bt * E_ + g * 4);
    const float4 ev = *(const float4*)(emb + (size_t)k * E_ + g * 4);
    xv.x += ev.x; xv.y += ev.y; xv.z += ev.z; xv.w += ev.w;
    *(float4*)(outp + (size_t)bt * E_ + g * 4) = xv;
}

// ---------- software-pipelined conv GEMM (A from LDS, B from L2) ----------
__device__ __forceinline__ void conv_gemm(const u16* xs, const u16* __restrict__ WT,
                                          int col0, int nl, int quad, f32x4 acc[4][4]) {
#pragma unroll
    for (int mt = 0; mt < 4; ++mt)
#pragma unroll
        for (int nt = 0; nt < 4; ++nt) acc[mt][nt] = (f32x4){0.f, 0.f, 0.f, 0.f};
    const u16* wp = WT + (size_t)col0 * KW + quad * 8;
    const u16* xp = xs + nl * XSTR + quad * 8;
    Frag aE[4], bE[4], aO[4], bO[4];
#pragma unroll
    for (int nt = 0; nt < 4; ++nt) bE[nt].u = *(const uint4*)(wp + nt * (16 * KW));
#pragma unroll
    for (int mt = 0; mt < 4; ++mt) aE[mt].u = *(const uint4*)(xp + (16 * mt) * XSTR);
#pragma unroll 1
    for (int s2 = 0; s2 < 12; ++s2) {
        const int s1 = 2 * s2 + 1;
        {
            const int kh = s1 >> 3, c0 = (s1 & 7) * 32;
#pragma unroll
            for (int nt = 0; nt < 4; ++nt)
                bO[nt].u = *(const uint4*)(wp + nt * (16 * KW) + s1 * 32);
#pragma unroll
            for (int mt = 0; mt < 4; ++mt)
                aO[mt].u = *(const uint4*)(xp + (16 * mt + kh) * XSTR + c0);
        }
#pragma unroll
        for (int mt = 0; mt < 4; ++mt)
#pragma unroll
            for (int nt = 0; nt < 4; ++nt)
                acc[mt][nt] = __builtin_amdgcn_mfma_f32_16x16x32_bf16(aE[mt].b, bE[nt].b, acc[mt][nt], 0, 0, 0);
        {
            const int s0 = (s1 + 1 < 24) ? s1 + 1 : 23;
            const int kh = s0 >> 3, c0 = (s0 & 7) * 32;
#pragma unroll
            for (int nt = 0; nt < 4; ++nt)
                bE[nt].u = *(const uint4*)(wp + nt * (16 * KW) + s0 * 32);
#pragma unroll
            for (int mt = 0; mt < 4; ++mt)
                aE[mt].u = *(const uint4*)(xp + (16 * mt + kh) * XSTR + c0);
        }
#pragma unroll
        for (int mt = 0; mt < 4; ++mt)
#pragma unroll
            for (int nt = 0; nt < 4; ++nt)
                acc[mt][nt] = __builtin_amdgcn_mfma_f32_16x16x32_bf16(aO[mt].b, bO[nt].b, acc[mt][nt], 0, 0, 0);
    }
}

// ---------- fused MFMA VariancePredictor block ----------
template <bool BF16>
__device__ void mfma_pred_block(
    int id, const void* __restrict__ Xv,
    const u16* __restrict__ WT1, const u16* __restrict__ WT2,
    const float* __restrict__ B1, const float* __restrict__ S1, const float* __restrict__ Bb1,
    const float* __restrict__ B2, const float* __restrict__ S2, const float* __restrict__ Bb2,
    const float* __restrict__ LW, const float* __restrict__ LB,
    float* __restrict__ out, MfmaSmem* sm) {
    const int tid = threadIdx.x;
    const int lane = tid & 63, w = tid >> 6;
    const int nl = lane & 15, quad = lane >> 4;
    const int b = id / NBLK, blk = id - b * NBLK;
    const int t0 = blk * MTW;

    if (BF16) {
        const u16* Xw = (const u16*)Xv + (size_t)b * T_ * E_;
        for (int it = 0; it < 9; ++it) {
            const int e = it * 256 + tid;
            if (e < XROWS * 32) {
                const int row = e >> 5, c8 = e & 31;
                const int tt = t0 - 2 + row;
                uint4 v = make_uint4(0u, 0u, 0u, 0u);
                if (tt >= 0 && tt < T_) v = *(const uint4*)(Xw + (size_t)tt * E_ + c8 * 8);
                *(uint4*)&sm->xs[row * XSTR + c8 * 8] = v;
            }
        }
    } else {
        const float* Xb = (const float*)Xv + (size_t)b * T_ * E_;
        for (int it = 0; it < 17; ++it) {
            const int e = it * 256 + tid;
            if (e < XROWS * 64) {
                const int row = e >> 6, c4 = e & 63;
                const int tt = t0 - 2 + row;
                float4 v = make_float4(0.f, 0.f, 0.f, 0.f);
                if (tt >= 0 && tt < T_) v = *(const float4*)(Xb + (size_t)tt * E_ + c4 * 4);
                uint2 pk = make_uint2((u32)f2b(v.x) | ((u32)f2b(v.y) << 16),
                                      (u32)f2b(v.z) | ((u32)f2b(v.w) << 16));
                *(uint2*)&sm->xs[row * XSTR + c4 * 4] = pk;
            }
        }
    }
    __syncthreads();

    const int col0 = w * 64 + nl;
    f32x4 acc[4][4];

    // ============ conv1 ============
    conv_gemm(sm->xs, WT1, col0, nl, quad, acc);

    float pb[4], ps[4], pbb[4];
#pragma unroll
    for (int nt = 0; nt < 4; ++nt) {
        pb[nt] = B1[col0 + nt * 16]; ps[nt] = S1[col0 + nt * 16]; pbb[nt] = Bb1[col0 + nt * 16];
    }
#pragma unroll
    for (int mt = 0; mt < 4; ++mt)
#pragma unroll
        for (int nt = 0; nt < 4; ++nt)
#pragma unroll
            for (int r = 0; r < 4; ++r)
                acc[mt][nt][r] = fmaxf(acc[mt][nt][r] + pb[nt], 0.f);
#pragma unroll
    for (int mt = 0; mt < 4; ++mt)
#pragma unroll
        for (int r = 0; r < 4; ++r) {
            float s = acc[mt][0][r] + acc[mt][1][r] + acc[mt][2][r] + acc[mt][3][r];
            float q = acc[mt][0][r] * acc[mt][0][r] + acc[mt][1][r] * acc[mt][1][r] +
                      acc[mt][2][r] * acc[mt][2][r] + acc[mt][3][r] * acc[mt][3][r];
#pragma unroll
            for (int off = 1; off < 16; off <<= 1) { s += __shfl_xor(s, off); q += __shfl_xor(q, off); }
            if (nl == 0) sm->red[16 * mt + 4 * quad + r][w] = make_float2(s, q);
        }
    __syncthreads();
    if (tid < MROWS) {
        const float2 p0 = sm->red[tid][0], p1 = sm->red[tid][1], p2 = sm->red[tid][2], p3 = sm->red[tid][3];
        const float s = p0.x + p1.x + p2.x + p3.x, q = p0.y + p1.y + p2.y + p3.y;
        const float m = s * (1.f / 256.f);
        const float var = q * (1.f / 256.f) - m * m;
        sm->m_l[tid] = m; sm->inv_l[tid] = 1.f / sqrtf(var + 1e-5f);
    }
    __syncthreads();
#pragma unroll
    for (int mt = 0; mt < 4; ++mt)
#pragma unroll
        for (int r = 0; r < 4; ++r) {
            const int row = 16 * mt + 4 * quad + r;
            const int th = t0 - 1 + row;
            const float mm = sm->m_l[row], iv = sm->inv_l[row];
#pragma unroll
            for (int nt = 0; nt < 4; ++nt) {
                float y = (acc[mt][nt][r] - mm) * iv * ps[nt] + pbb[nt];
                if (th < 0 || th >= T_) y = 0.f;
                sm->xs[row * XSTR + col0 + nt * 16] = f2b(y);
            }
        }
    __syncthreads();

    // ============ conv2 ============
    conv_gemm(sm->xs, WT2, col0, nl, quad, acc);

#pragma unroll
    for (int nt = 0; nt < 4; ++nt) {
        pb[nt] = B2[col0 + nt * 16]; ps[nt] = S2[col0 + nt * 16]; pbb[nt] = Bb2[col0 + nt * 16];
    }
#pragma unroll
    for (int mt = 0; mt < 4; ++mt)
#pragma unroll
        for (int nt = 0; nt < 4; ++nt)
#pragma unroll
            for (int r = 0; r < 4; ++r)
                acc[mt][nt][r] = fmaxf(acc[mt][nt][r] + pb[nt], 0.f);
#pragma unroll
    for (int mt = 0; mt < 4; ++mt)
#pragma unroll
        for (int r = 0; r < 4; ++r) {
            float s = acc[mt][0][r] + acc[mt][1][r] + acc[mt][2][r] + acc[mt][3][r];
            float q = acc[mt][0][r] * acc[mt][0][r] + acc[mt][1][r] * acc[mt][1][r] +
                      acc[mt][2][r] * acc[mt][2][r] + acc[mt][3][r] * acc[mt][3][r];
#pragma unroll
            for (int off = 1; off < 16; off <<= 1) { s += __shfl_xor(s, off); q += __shfl_xor(q, off); }
            if (nl == 0) sm->red[16 * mt + 4 * quad + r][w] = make_float2(s, q);
        }
    __syncthreads();
    if (tid < MROWS) {
        const float2 p0 = sm->red[tid][0], p1 = sm->red[tid][1], p2 = sm->red[tid][2], p3 = sm->red[tid][3];
        const float s = p0.x + p1.x + p2.x + p3.x, q = p0.y + p1.y + p2.y + p3.y;
        const float m = s * (1.f / 256.f);
        const float var = q * (1.f / 256.f) - m * m;
        sm->m_l[tid] = m; sm->inv_l[tid] = 1.f / sqrtf(var + 1e-5f);
    }
    __syncthreads();
    float lwv[4];
#pragma unroll
    for (int nt = 0; nt < 4; ++nt) lwv[nt] = LW[col0 + nt * 16];
#pragma unroll
    for (int mt = 0; mt < 4; ++mt)
#pragma unroll
        for (int r = 0; r < 4; ++r) {
            const int row = 16 * mt + 4 * quad + r;
            const float mm = sm->m_l[row], iv = sm->inv_l[row];
            float z = 0.f;
#pragma unroll
            for (int nt = 0; nt < 4; ++nt) {
                const float y = (acc[mt][nt][r] - mm) * iv * ps[nt] + pbb[nt];
                z = fmaf(y, lwv[nt], z);
            }
#pragma unroll
            for (int off = 1; off < 16; off <<= 1) z += __shfl_xor(z, off);
            if (nl == 0) sm->red[row][w].x = z;
        }
    __syncthreads();
    if (tid < MTW) {
        const int t = t0 + tid;
        if (t < T_) {
            const float z = sm->red[tid][0].x + sm->red[tid][1].x + sm->red[tid][2].x + sm->red[tid][3].x + LB[0];
            out[b * T_ + t] = z;
        }
    }
}

// ---------- fp32 duration predictor block ----------
__device__ void dur_block(
    int id, const float* __restrict__ X, const float* __restrict__ W1,
    const float* __restrict__ B1, const float* __restrict__ S1, const float* __restrict__ Bb1,
    const float* __restrict__ W2, const float* __restrict__ B2, const float* __restrict__ S2,
    const float* __restrict__ Bb2, const float* __restrict__ LW, const float* __restrict__ LB,
    const int* __restrict__ dscale, float* __restrict__ out, DurSmem* sm) {
    const int tid = threadIdx.x;
    const int lane = tid & 63, wv = tid >> 6;
    const int m0 = id * TW;
    const int b = m0 >> 9;           // L_ = 512
    const int t0 = m0 & (L_ - 1);
    const float* Xb = X + (size_t)b * L_ * E_;

#pragma unroll
    for (int s = 0; s < NX; ++s) {
        const int tt = t0 - 2 + s;
        float v = 0.f;
        if (tt >= 0 && tt < L_) v = Xb[(size_t)tt * E_ + tid];
        sm->buf[tid * RS + s] = v;
    }
    __syncthreads();

    float a1[NH];
#pragma unroll
    for (int r = 0; r < NH; ++r) a1[r] = 0.f;
    {
        const float* Wf = W1 + tid;
        for (int c = 0; c < E_; ++c) {
            const float4* xq = (const float4*)(&sm->buf[c * RS]);
            const float4 q0 = xq[0], q1 = xq[1], q2 = xq[2], q3 = xq[3], q4 = xq[4];
            const float xr[NX] = {q0.x, q0.y, q0.z, q0.w, q1.x, q1.y, q1.z, q1.w,
                                  q2.x, q2.y, q2.z, q2.w, q3.x, q3.y, q3.z, q3.w,
                                  q4.x, q4.y, q4.z, q4.w};
            const float w0 = Wf[(0 * E_ + c) * F_];
            const float w1 = Wf[(1 * E_ + c) * F_];
            const float w2 = Wf[(2 * E_ + c) * F_];
#pragma unroll
            for (int r = 0; r < NH; ++r) {
                a1[r] = fmaf(xr[r],     w0, a1[r]);
                a1[r] = fmaf(xr[r + 1], w1, a1[r]);
                a1[r] = fmaf(xr[r + 2], w2, a1[r]);
            }
        }
    }
    __syncthreads();

    const float b1f = B1[tid];
#pragma unroll
    for (int r = 0; r < NH; ++r) a1[r] = fmaxf(a1[r] + b1f, 0.f);

#pragma unroll
    for (int r = 0; r < NH; ++r) {
        float s = a1[r], q = a1[r] * a1[r];
#pragma unroll
        for (int off = 32; off; off >>= 1) { s += __shfl_xor(s, off); q += __shfl_xor(q, off); }
        if (lane == 0) { sm->red_s[r][wv] = s; sm->red_q[r][wv] = q; }
    }
    __syncthreads();
    if (tid < NH) {
        const float s = sm->red_s[tid][0] + sm->red_s[tid][1] + sm->red_s[tid][2] + sm->red_s[tid][3];
        const float q = sm->red_q[tid][0] + sm->red_q[tid][1] + sm->red_q[tid][2] + sm->red_q[tid][3];
        const float m = s * (1.f / F_);
        const float v = q * (1.f / F_) - m * m;
        sm->m_l[tid] = m;
        sm->inv_l[tid] = 1.f / sqrtf(v + 1e-5f);
    }
    __syncthreads();

    const float s1f = S1[tid], sb1 = Bb1[tid];
#pragma unroll
    for (int r = 0; r < NH; ++r) {
        const int th = t0 - 1 + r;
        float y = (a1[r] - sm->m_l[r]) * sm->inv_l[r] * s1f + sb1;
        if (th < 0 || th >= L_) y = 0.f;
        sm->buf[tid * RS + r] = y;
    }
    __syncthreads();

    float a2[TW];
#pragma unroll
    for (int p = 0; p < TW; ++p) a2[p] = 0.f;
    {
        const float* Wf = W2 + tid;
        for (int c = 0; c < E_; ++c) {
            const float4* xq = (const float4*)(&sm->buf[c * RS]);
            const float4 q0 = xq[0], q1 = xq[1], q2 = xq[2], q3 = xq[3], q4 = xq[4];
            const float xr[NX] = {q0.x, q0.y, q0.z, q0.w, q1.x, q1.y, q1.z, q1.w,
                                  q2.x, q2.y, q2.z, q2.w, q3.x, q3.y, q3.z, q3.w,
                                  q4.x, q4.y, q4.z, q4.w};
            const float w0 = Wf[(0 * E_ + c) * F_];
            const float w1 = Wf[(1 * E_ + c) * F_];
            const float w2 = Wf[(2 * E_ + c) * F_];
#pragma unroll
            for (int p = 0; p < TW; ++p) {
                a2[p] = fmaf(xr[p],     w0, a2[p]);
                a2[p] = fmaf(xr[p + 1], w1, a2[p]);
                a2[p] = fmaf(xr[p + 2], w2, a2[p]);
            }
        }
    }

    const float b2ff = B2[tid];
    float r_[TW];
#pragma unroll
    for (int p = 0; p < TW; ++p) r_[p] = fmaxf(a2[p] + b2ff, 0.f);

#pragma unroll
    for (int p = 0; p < TW; ++p) {
        float s = r_[p], q = r_[p] * r_[p];
#pragma unroll
        for (int off = 32; off; off >>= 1) { s += __shfl_xor(s, off); q += __shfl_xor(q, off); }
        if (lane == 0) { sm->red_s[p][wv] = s; sm->red_q[p][wv] = q; }
    }
    __syncthreads();
    if (tid < TW) {
        const float s = sm->red_s[tid][0] + sm->red_s[tid][1] + sm->red_s[tid][2] + sm->red_s[tid][3];
        const float q = sm->red_q[tid][0] + sm->red_q[tid][1] + sm->red_q[tid][2] + sm->red_q[tid][3];
        const float m = s * (1.f / F_);
        const float v = q * (1.f / F_) - m * m;
        sm->m_l[tid] = m;
        sm->inv_l[tid] = 1.f / sqrtf(v + 1e-5f);
    }
    __syncthreads();

    const float s2f = S2[tid], sb2 = Bb2[tid];
    const float lwf = LW[tid];
#pragma unroll
    for (int p = 0; p < TW; ++p) {
        const float y = (r_[p] - sm->m_l[p]) * sm->inv_l[p] * s2f + sb2;
        float z = y * lwf;
#pragma unroll
        for (int off = 32; off; off >>= 1) z += __shfl_xor(z, off);
        if (lane == 0) sm->red_s[p][wv] = z;
    }
    __syncthreads();
    if (tid < TW) {
        float z = sm->red_s[tid][0] + sm->red_s[tid][1] + sm->red_s[tid][2] + sm->red_s[tid][3] + LB[0];
        const float e = expf(z) * (float)dscale[0];
        out[m0 + tid] = fmaxf(rintf(e), 0.f);
    }
}

// ---------- ve block: ove = b2f(x2) + eemb[ebkt] ----------
__device__ void ve_block(int id, const u16* __restrict__ x2w, const int* __restrict__ ebkt,
                         const float* __restrict__ eemb, float* __restrict__ ve) {
#pragma unroll
    for (int it = 0; it < 16; ++it) {
        const int k = id * 4096 + it * 256 + threadIdx.x;    // float4 id
        const int bt = k >> 6, c4 = k & 63;
        const int kb = ebkt[bt];
        const uint2 xv = *(const uint2*)(x2w + (size_t)bt * E_ + c4 * 4);
        const float4 ev = *(const float4*)(eemb + (size_t)kb * E_ + c4 * 4);
        float4 o;
        o.x = blo(xv.x) + ev.x; o.y = bhi(xv.x) + ev.y;
        o.z = blo(xv.y) + ev.z; o.w = bhi(xv.y) + ev.w;
        *(float4*)(ve + (size_t)k * 4) = o;
    }
}

// ---------- dispatch P: pitch MFMA (2144) + duration fp32 (1024), interleaved ----------
template <bool BF16>
__global__ __launch_bounds__(256) void dispatchP_kernel(
    const void* __restrict__ Xv, const u16* __restrict__ wt,
    const float* __restrict__ hidden, const int* __restrict__ dscale,
    const float* __restrict__ w1, const float* __restrict__ b1,
    const float* __restrict__ s1, const float* __restrict__ bb1,
    const float* __restrict__ w2, const float* __restrict__ b2,
    const float* __restrict__ s2, const float* __restrict__ bb2,
    const float* __restrict__ lw, const float* __restrict__ lb,
    float* __restrict__ out_dur, float* __restrict__ out_pitch) {
    __shared__ SmemU sm;
    const int bx = blockIdx.x;
    if (bx < 3072 && (bx % 3) == 1) {
        dur_block(bx / 3, hidden, w1, b1, s1, bb1, w2, b2, s2, bb2, lw, lb, dscale, out_dur, &sm.d);
        return;
    }
    const int mid = bx - ((bx < 3072) ? (bx + 2) / 3 : 1024);
    mfma_pred_block<BF16>(mid, Xv, wt + 0 * WMAT, wt + 1 * WMAT,
        b1 + F_, s1 + F_, bb1 + F_, b2 + F_, s2 + F_, bb2 + F_,
        lw + F_, lb + 1, out_pitch, &sm.m);
}

// ---------- dispatch E: energy MFMA (2144) + ve assembly (2048), interleaved ----------
__global__ __launch_bounds__(256) void dispatchE_kernel(
    const u16* __restrict__ x2w, const u16* __restrict__ wt,
    const int* __restrict__ ebkt, const float* __restrict__ eemb,
    const float* __restrict__ b1, const float* __restrict__ s1, const float* __restrict__ bb1,
    const float* __restrict__ b2, const float* __restrict__ s2, const float* __restrict__ bb2,
    const float* __restrict__ lw, const float* __restrict__ lb,
    float* __restrict__ out_energy, float* __restrict__ ve) {
    __shared__ SmemU sm;
    const int bx = blockIdx.x;
    if (bx < 4096 && (bx & 1)) {
        ve_block(bx >> 1, x2w, ebkt, eemb, ve);
        return;
    }
    const int mid = (bx < 4096) ? (bx >> 1) : (bx - 2048);
    mfma_pred_block<true>(mid, x2w, wt + 2 * WMAT, wt + 3 * WMAT,
        b1 + 2 * F_, s1 + 2 * F_, bb1 + 2 * F_, b2 + 2 * F_, s2 + 2 * F_, bb2 + 2 * F_,
        lw + 2 * F_, lb + 2, out_energy, &sm.m);
}

// ---------- fallback energy-only MFMA (fp32 source) ----------
__global__ __launch_bounds__(256) void mfmaE_kernel(
    const float* __restrict__ X, const u16* __restrict__ wt,
    const float* __restrict__ b1, const float* __restrict__ s1, const float* __restrict__ bb1,
    const float* __restrict__ b2, const float* __restrict__ s2, const float* __restrict__ bb2,
    const float* __restrict__ lw, const float* __restrict__ lb,
    float* __restrict__ out_energy) {
    __shared__ SmemU sm;
    mfma_pred_block<false>(blockIdx.x, X, wt + 2 * WMAT, wt + 3 * WMAT,
        b1 + 2 * F_, s1 + 2 * F_, bb1 + 2 * F_, b2 + 2 * F_, s2 + 2 * F_, bb2 + 2 * F_,
        lw + 2 * F_, lb + 2, out_energy, &sm.m);
}

extern "C" void kernel_launch(void* const* d_in, const int* in_sizes, int n_in,
                              void* d_out, int out_size, void* d_ws, size_t ws_size,
                              hipStream_t stream) {
    (void)in_sizes; (void)n_in; (void)out_size;
    const float* hidden = (const float*)d_in[0];
    const int*   dur    = (const int*)d_in[3];
    const float* pt     = (const float*)d_in[4];
    const float* et     = (const float*)d_in[5];
    const int*   dscale = (const int*)d_in[6];
    const float* w1  = (const float*)d_in[7];
    const float* b1  = (const float*)d_in[8];
    const float* s1  = (const float*)d_in[9];
    const float* bb1 = (const float*)d_in[10];
    const float* w2  = (const float*)d_in[11];
    const float* b2  = (const float*)d_in[12];
    const float* s2  = (const float*)d_in[13];
    const float* bb2 = (const float*)d_in[14];
    const float* lw  = (const float*)d_in[15];
    const float* lb  = (const float*)d_in[16];
    const float* pbins = (const float*)d_in[17];
    const float* pemb  = (const float*)d_in[18];
    const float* ebins = (const float*)d_in[19];
    const float* eemb  = (const float*)d_in[20];

    float* out        = (float*)d_out;
    float* out_dur    = out;
    float* out_pitch  = out + 16384;
    float* out_energy = out + 147456;
    float* ove        = out + 278528;            // B*T*E fp32

    char* ws = (char*)d_ws;
    u16* wt = (u16*)ws;                          // 1.5 MiB transposed bf16 weights
    int* pbkt = (int*)(ws + 1572864);
    int* ebkt = (int*)(ws + 2097152);
    u16* xw   = (u16*)(ws + 2621440);            // bf16 x, 64 MiB
    const size_t NEED = 2621440u + (size_t)B_ * T_ * E_ * 2u;

    prep_w_kernel<<<(4 * WMAT) / 256, 256, 0, stream>>>(w1, w2, wt);

    if (ws_size >= NEED) {
        // ---- fast path: bf16 x pipeline in ws ----
        bucket_kernel<<<(B_ * T_) / 256, 256, 0, stream>>>(pt, et, pbins, ebins, pbkt, ebkt);
        lr_gather_kernel<true><<<B_ * (T_ / 128), 512, 0, stream>>>(hidden, dur, xw, nullptr);
        dispatchP_kernel<true><<<3168, 256, 0, stream>>>(
            xw, wt, hidden, dscale, w1, b1, s1, bb1, w2, b2, s2, bb2, lw, lb,
            out_dur, out_pitch);
        x2_kernel<<<2048, 256, 0, stream>>>(xw, pbkt, pemb);
        dispatchE_kernel<<<4192, 256, 0, stream>>>(
            xw, wt, ebkt, eemb, b1, s1, bb1, b2, s2, bb2, lw, lb, out_energy, ove);
    } else {
        // ---- fallback: fp32 x in ove (round-4 proven), dur still merged ----
        lr_gather_kernel<false><<<B_ * (T_ / 128), 512, 0, stream>>>(hidden, dur, nullptr, ove);
        dispatchP_kernel<false><<<3168, 256, 0, stream>>>(
            ove, wt, hidden, dscale, w1, b1, s1, bb1, w2, b2, s2, bb2, lw, lb,
            out_dur, out_pitch);
        addemb_kernel<<<(B_ * T_ * 64) / 256, 256, 0, stream>>>(ove, pt, pbins, pemb, ove);
        mfmaE_kernel<<<NMFMA, 256, 0, stream>>>(
            ove, wt, b1, s1, bb1, b2, s2, bb2, lw, lb, out_energy);
        addemb_kernel<<<(B_ * T_ * 64) / 256, 256, 0, stream>>>(ove, et, ebins, eemb, ove);
    }
}